// Round 10
// baseline (142.834 us; speedup 1.0000x reference)
//
#include <hip/hip_runtime.h>

#define NB 2
#define NCK 8                    // tracked components 1..8 (comp 0 dropped)
#define NVAL (NCK * 2)           // {inter,count} x 8 per batch
#define NSL 32                   // 32 values: b0[16] | b1[16]
#define NREP 64                  // replica rows for contention-free global atomics
#define SMOOTHF 1e-5f

// rep[NREP*NSL] + ticket
__global__ __launch_bounds__(256) void cc_zero(float* __restrict__ rep,
                                               int* __restrict__ ticket) {
    ((float4*)rep)[threadIdx.x] = make_float4(0.f, 0.f, 0.f, 0.f);
    ((float4*)rep)[threadIdx.x + 256] = make_float4(0.f, 0.f, 0.f, 0.f);
    if (threadIdx.x == 0) *ticket = 0;
}

#define PROC(A0, A1, T, C) do { \
    const float d_ = (A0) - (A1); \
    const float p_ = 1.0f / (1.0f + __expf((T) ? d_ : -d_)); \
    float2 s_ = bins[C][threadIdx.x]; \
    s_.x += p_; s_.y += 1.0f; \
    bins[C][threadIdx.x] = s_; \
    } while (0)

// Bin-major LDS bins[c][tid]: bank = (2*lane+part)%32, independent of the
// data-dependent c (512%32==0). Proven conflict-free (R8: 2.1M -> 16K).
__global__ __launch_bounds__(256) void cc_accum(
        const float* __restrict__ y_pred,
        const int* __restrict__ y,
        const int* __restrict__ comp,
        float* __restrict__ rep,       // [NREP][NSL]
        int* __restrict__ ticket,
        float* __restrict__ out,
        int V4, int BPB, int nblk) {
    __shared__ __align__(8) float2 bins[9][256];   // 18432 B
    __shared__ float redbuf[16 * 17];              // 1088 B
    __shared__ int lastflag;                       // overlay final scratch on bins

    #pragma unroll
    for (int i = 0; i < 9; ++i) bins[i][threadIdx.x] = make_float2(0.0f, 0.0f);
    // no barrier: each thread touches only its own column until drain

    const int b   = (blockIdx.x >= BPB) ? 1 : 0;   // batch is block-uniform
    const int blk = blockIdx.x - b * BPB;
    const int stride = BPB * 256;

    const float4* p0q = (const float4*)(y_pred + (size_t)b * 2 * ((size_t)V4 * 4));
    const float4* p1q = p0q + (size_t)V4;
    const int4* yq = (const int4*)y    + (size_t)b * V4;
    const int4* cq = (const int4*)comp + (size_t)b * V4;

    // Software-pipelined rotated loop: prefetch i+1, pin issue, process i.
    int v = blk * 256 + threadIdx.x;
    if (v < V4) {
        float4 A0 = p0q[v], A1 = p1q[v];
        int4 T = yq[v], C = cq[v];
        while (true) {
            const int vn = v + stride;
            const bool mn = vn < V4;
            const int vc = mn ? vn : 0;            // clamped prefetch, never processed if invalid
            const float4 B0 = p0q[vc];
            const float4 B1 = p1q[vc];
            const int4 Tn = yq[vc];
            const int4 Cn = cq[vc];
            __builtin_amdgcn_sched_barrier(0);     // prefetch issued BEFORE compute
            PROC(A0.x, A1.x, T.x, C.x);
            PROC(A0.y, A1.y, T.y, C.y);
            PROC(A0.z, A1.z, T.z, C.z);
            PROC(A0.w, A1.w, T.w, C.w);
            if (!mn) break;
            A0 = B0; A1 = B1; T = Tn; C = Cn;
            v = vn;
        }
    }
    __syncthreads();

    // Drain: value vv = tid>>4 (= 2*(comp-1)+part), chunk q = tid&15 sums
    // columns q+16k. bank = (2q+part)%32 -> thread-determined, conflict-free.
    {
        const int vv = threadIdx.x >> 4, q = threadIdx.x & 15;
        const int c  = (vv >> 1) + 1, part = vv & 1;
        const float* base = (const float*)&bins[c][0];
        float s = 0.0f;
        #pragma unroll
        for (int k = 0; k < 16; ++k)
            s += base[(q + 16 * k) * 2 + part];
        redbuf[vv * 17 + q] = s;
    }
    __syncthreads();
    // Publish: 16 atomics into this block's replica row (<=32 colliders/addr,
    // spread over block completion times — proven cheap in R9).
    if (threadIdx.x < NVAL) {
        const int j = threadIdx.x;
        float s = 0.0f;
        #pragma unroll
        for (int q = 0; q < 16; ++q) s += redbuf[j * 17 + q];
        atomicAdd(&rep[(size_t)(blockIdx.x & (NREP - 1)) * NSL + b * NVAL + j], s);
        __threadfence();                           // release my adds
    }
    __syncthreads();
    if (threadIdx.x == 0) {
        __threadfence();
        lastflag = (atomicAdd(ticket, 1) == nblk - 1) ? 1 : 0;
    }
    __syncthreads();

    if (lastflag) {                                // block-uniform: last block finalizes
        __threadfence();                           // acquire
        float* red2 = (float*)&bins[0][0];         // overlay: bins dead now
        const int tid = threadIdx.x;
        const int j = tid & 31, g = tid >> 5;      // 8 groups x 32 values
        float s = 0.0f;
        #pragma unroll
        for (int k = 0; k < NREP / 8; ++k)         // PARALLEL coherent loads (R8 fix)
            s += __hip_atomic_load(&rep[(size_t)(g * (NREP / 8) + k) * NSL + j],
                                   __ATOMIC_RELAXED, __HIP_MEMORY_SCOPE_AGENT);
        red2[g * NSL + j] = s;
        __syncthreads();
        if (tid < NSL) {
            float t = 0.0f;
            #pragma unroll
            for (int gg = 0; gg < 8; ++gg) t += red2[gg * NSL + tid];
            redbuf[tid] = t;                       // fin[32]
        }
        __syncthreads();
        if (tid == 0) {
            // psum = tsum = count (softmax over 2 ch sums to 1; one-hot sums to 1)
            float total = 0.0f;
            for (int bb = 0; bb < NB; ++bb) {
                float dsum = 0.0f, pc = 0.0f;
                for (int jj = 0; jj < NCK; ++jj) {
                    const float inter = redbuf[bb * NVAL + 2 * jj];
                    const float cnt   = redbuf[bb * NVAL + 2 * jj + 1];
                    if (cnt > 0.0f) {
                        dsum += 1.0f - (2.0f * inter + SMOOTHF) / (2.0f * cnt + SMOOTHF);
                        pc += 1.0f;
                    }
                }
                total += dsum / fmaxf(pc, 1.0f);
            }
            out[0] = total / (float)NB;
        }
    }
}

extern "C" void kernel_launch(void* const* d_in, const int* in_sizes, int n_in,
                              void* d_out, int out_size, void* d_ws, size_t ws_size,
                              hipStream_t stream) {
    const float* y_pred = (const float*)d_in[0];
    const int*   y      = (const int*)d_in[1];
    const int*   comp   = (const int*)d_in[2];
    float* out = (float*)d_out;
    float* rep = (float*)d_ws;                     // NREP*NSL = 2048 floats = 8 KB
    int* ticket = (int*)(rep + NREP * NSL);

    const int nvox = in_sizes[1];    // B * V = 8,192,000
    const int V    = nvox / NB;      // 4,096,000
    const int V4   = V / 4;          // 1,024,000 quads per batch

    int BPB = 1024;                  // blocks per batch -> 2048 total = 8/CU
    if (BPB > V4) BPB = V4;
    if (BPB < 1) BPB = 1;
    const int nblk = 2 * BPB;

    cc_zero <<<dim3(1),    dim3(256), 0, stream>>>(rep, ticket);
    cc_accum<<<dim3(nblk), dim3(256), 0, stream>>>(y_pred, y, comp, rep, ticket, out,
                                                   V4, BPB, nblk);
}

// Round 11
// 31.916 us; speedup vs baseline: 4.4752x; 4.4752x over previous
//
#include <hip/hip_runtime.h>

#define NB 2
#define NCK 8                    // tracked components 1..8 (comp 0 dropped)
#define NVAL (NCK * 2)           // {inter,count} x 8 per batch
#define NBINS (NB * NVAL)        // 32 global bins
#define SMOOTHF 1e-5f

// Bin-major LDS bins[c][tid]: addr(float) = c*512 + tid*2 + part ->
// bank = (2*lane+part)%32, independent of the data-dependent component c
// (512%32==0) and wave id (128%32==0). Proven: conflicts 2.1M -> 16K (R8).
#define PROC(A0, A1, T, C) do { \
    const float d_ = (A0) - (A1); \
    const float p_ = 1.0f / (1.0f + __expf((T) ? d_ : -d_)); \
    float2 s_ = bins[C][threadIdx.x]; \
    s_.x += p_; s_.y += 1.0f; \
    bins[C][threadIdx.x] = s_; \
    } while (0)

__global__ __launch_bounds__(256) void cc_accum(
        const float* __restrict__ y_pred,
        const int* __restrict__ y,
        const int* __restrict__ comp,
        float* __restrict__ partial,   // [NBINS][nblk], column = global blockIdx
        int V4, int BPB, int nblk) {
    __shared__ __align__(8) float2 bins[9][256];
    __shared__ float redbuf[16 * 17];   // [vv][q], stride 17

    #pragma unroll
    for (int i = 0; i < 9; ++i) bins[i][threadIdx.x] = make_float2(0.0f, 0.0f);
    // no barrier: each thread touches only its own column until drain

    const int b   = (blockIdx.x >= BPB) ? 1 : 0;   // batch is block-uniform
    const int blk = blockIdx.x - b * BPB;
    const int stride = BPB * 256;

    const float4* p0q = (const float4*)(y_pred + (size_t)b * 2 * ((size_t)V4 * 4));
    const float4* p1q = p0q + (size_t)V4;
    const int4* yq = (const int4*)y    + (size_t)b * V4;
    const int4* cq = (const int4*)comp + (size_t)b * V4;

    // Grid-stride, unrolled x2: 8 vector loads issued per iteration in program
    // order; compiler schedules freely (NO sched_barrier — R10 lesson).
    int v = blk * 256 + threadIdx.x;
    for (; v + stride < V4; v += 2 * stride) {
        const int v2 = v + stride;
        const float4 a0 = p0q[v];
        const float4 a1 = p1q[v];
        const int4 t  = yq[v];
        const int4 c  = cq[v];
        const float4 b0 = p0q[v2];
        const float4 b1 = p1q[v2];
        const int4 t2 = yq[v2];
        const int4 c2 = cq[v2];

        PROC(a0.x, a1.x, t.x, c.x);
        PROC(a0.y, a1.y, t.y, c.y);
        PROC(a0.z, a1.z, t.z, c.z);
        PROC(a0.w, a1.w, t.w, c.w);
        PROC(b0.x, b1.x, t2.x, c2.x);
        PROC(b0.y, b1.y, t2.y, c2.y);
        PROC(b0.z, b1.z, t2.z, c2.z);
        PROC(b0.w, b1.w, t2.w, c2.w);
    }
    if (v < V4) {
        const float4 a0 = p0q[v];
        const float4 a1 = p1q[v];
        const int4 t = yq[v];
        const int4 c = cq[v];
        PROC(a0.x, a1.x, t.x, c.x);
        PROC(a0.y, a1.y, t.y, c.y);
        PROC(a0.z, a1.z, t.z, c.z);
        PROC(a0.w, a1.w, t.w, c.w);
    }
    __syncthreads();

    // Drain: value vv = tid>>4 (= 2*(comp-1)+part), chunk q = tid&15 sums
    // columns q+16k. bank = (2q+part)%32 -> thread-determined, conflict-free.
    {
        const int vv = threadIdx.x >> 4, q = threadIdx.x & 15;
        const int c  = (vv >> 1) + 1, part = vv & 1;
        const float* base = (const float*)&bins[c][0];
        float s = 0.0f;
        #pragma unroll
        for (int k = 0; k < 16; ++k)
            s += base[(q + 16 * k) * 2 + part];
        redbuf[vv * 17 + q] = s;
    }
    __syncthreads();
    if (threadIdx.x < NVAL) {
        const int j = threadIdx.x;
        float s = 0.0f;
        #pragma unroll
        for (int q = 0; q < 16; ++q) s += redbuf[j * 17 + q];
        partial[(size_t)(b * NVAL + j) * nblk + blockIdx.x] = s;
    }
}

__global__ __launch_bounds__(256) void cc_reduce(
        const float* __restrict__ partial, float* __restrict__ fin,
        int half, int nblk) {
    const int bin = blockIdx.x;            // 0..NBINS-1
    const int b = (bin >= NVAL) ? 1 : 0;   // which batch's columns hold data
    const int c0 = b * half;
    float s = 0.0f;
    for (int i = threadIdx.x; i < half; i += 256)
        s += partial[(size_t)bin * nblk + c0 + i];
    #pragma unroll
    for (int off = 32; off; off >>= 1) s += __shfl_xor(s, off);
    __shared__ float w4[4];
    if ((threadIdx.x & 63) == 0) w4[threadIdx.x >> 6] = s;
    __syncthreads();
    if (threadIdx.x == 0) fin[bin] = w4[0] + w4[1] + w4[2] + w4[3];
}

__global__ void cc_final(const float* __restrict__ fin, float* __restrict__ out) {
    // psum = tsum = count (softmax over 2 ch sums to 1; one-hot sums to 1).
    float total = 0.0f;
    for (int b = 0; b < NB; ++b) {
        float dsum = 0.0f, pc = 0.0f;
        for (int j = 0; j < NCK; ++j) {
            const float inter = fin[b * NVAL + 2 * j];
            const float cnt   = fin[b * NVAL + 2 * j + 1];
            if (cnt > 0.0f) {
                dsum += 1.0f - (2.0f * inter + SMOOTHF) / (2.0f * cnt + SMOOTHF);
                pc += 1.0f;
            }
        }
        total += dsum / fmaxf(pc, 1.0f);
    }
    out[0] = total / (float)NB;
}

extern "C" void kernel_launch(void* const* d_in, const int* in_sizes, int n_in,
                              void* d_out, int out_size, void* d_ws, size_t ws_size,
                              hipStream_t stream) {
    const float* y_pred = (const float*)d_in[0];
    const int*   y      = (const int*)d_in[1];
    const int*   comp   = (const int*)d_in[2];
    float* out = (float*)d_out;
    float* ws  = (float*)d_ws;

    const int nvox = in_sizes[1];    // B * V = 8,192,000
    const int V    = nvox / NB;      // 4,096,000
    const int V4   = V / 4;          // 1,024,000 quads per batch

    int BPB = 1024;                  // blocks per batch -> 2048 total = 8/CU
    int cap_rows = (int)((ws_size / sizeof(float) - NBINS) / NBINS);
    if (2 * BPB > cap_rows) BPB = cap_rows / 2;
    if (BPB > V4) BPB = V4;
    if (BPB < 1) BPB = 1;
    const int nblk = 2 * BPB;

    float* fin = ws + (size_t)NBINS * nblk;

    cc_accum<<<dim3(nblk), dim3(256), 0, stream>>>(y_pred, y, comp, ws, V4, BPB, nblk);
    cc_reduce<<<dim3(NBINS), dim3(256), 0, stream>>>(ws, fin, BPB, nblk);
    cc_final<<<dim3(1), dim3(1), 0, stream>>>(fin, out);
}